// Round 11
// baseline (331.807 us; speedup 1.0000x reference)
//
#include <hip/hip_runtime.h>
#include <stdint.h>

typedef unsigned short u16;
typedef unsigned int u32;
typedef __attribute__((ext_vector_type(8))) short bf16x8;
typedef __attribute__((ext_vector_type(4))) float f32x4;

// ---------- helpers ----------
// GROUND TRUTH (R2-R4/R8-R10 pass vs R5-R7 NaN): inputs fp32, output fp32.
// Intermediates bf16 (absmax 0.0039 << 0.0123 threshold).
__device__ __forceinline__ float bf2f(u32 u) {
    union { u32 i; float f; } v; v.i = u << 16; return v.f;
}
__device__ __forceinline__ u16 f2bf(float f) {
    u32 x = __float_as_uint(f);
    return (u16)((x + 0x7fffu + ((x >> 16) & 1u)) >> 16);
}
__device__ __forceinline__ float wred_sum(float v) {
#pragma unroll
    for (int o = 32; o > 0; o >>= 1) v += __shfl_xor(v, o, 64);
    return v;
}
// A-fragment: 8 consecutive f32 -> bf16x8 (proven R8-R10)
__device__ __forceinline__ bf16x8 ldA_f32(const float* p, size_t off) {
    union { uint4 u; bf16x8 b; } t;
    const float* af = p + off;
    float4 a = *(const float4*)af, b2 = *(const float4*)(af + 4);
    t.u.x = (u32)f2bf(a.x)  | ((u32)f2bf(a.y)  << 16);
    t.u.y = (u32)f2bf(a.z)  | ((u32)f2bf(a.w)  << 16);
    t.u.z = (u32)f2bf(b2.x) | ((u32)f2bf(b2.y) << 16);
    t.u.w = (u32)f2bf(b2.z) | ((u32)f2bf(b2.w) << 16);
    return t.b;
}
// A-fragment from bf16 row (global or LDS) (proven R8-R10)
__device__ __forceinline__ bf16x8 ld16B(const u16* p, size_t off) {
    union { uint4 u; bf16x8 b; } t; t.u = *(const uint4*)(p + off); return t.b;
}
// B-fragment from padded LDS weight tile [128][136] (proven R8-R10)
__device__ __forceinline__ bf16x8 ldB(const u16* sw, int ct, int ks, int l16, int quad) {
    union { uint4 u; bf16x8 b; } t;
    t.u = *(const uint4*)&sw[(ct * 16 + l16) * 136 + ks * 32 + quad * 8];
    return t.b;
}
// cooperative stage of a [128 x 128] f32 weight chunk -> bf16 LDS [128][136], 256 thr
__device__ __forceinline__ void stage256_f32(const float* W, int stride, int koff,
                                             u16* sw, int tid) {
#pragma unroll
    for (int it = 0; it < 8; ++it) {
        int idx = (it * 256 + tid) * 8;
        int c = idx >> 7, kk = idx & 127;
        const float* wf = W + (size_t)c * stride + koff + kk;
        float4 a = *(const float4*)wf, b = *(const float4*)(wf + 4);
        uint4 v;
        v.x = (u32)f2bf(a.x) | ((u32)f2bf(a.y) << 16);
        v.y = (u32)f2bf(a.z) | ((u32)f2bf(a.w) << 16);
        v.z = (u32)f2bf(b.x) | ((u32)f2bf(b.y) << 16);
        v.w = (u32)f2bf(b.z) | ((u32)f2bf(b.w) << 16);
        *(uint4*)&sw[c * 136 + kk] = v;
    }
}

// ---------- CSR build ----------
__global__ void k_zero(int* __restrict__ p, int n) {
    int i = blockIdx.x * 256 + threadIdx.x;
    if (i < n) p[i] = 0;
}
// 4 edges/thread, vectorized reads
__global__ void k_hist(const int* __restrict__ dst, int E, int* __restrict__ deg) {
    int i0 = (blockIdx.x * 256 + threadIdx.x) * 4;
    if (i0 + 3 < E) {
        int4 d = *(const int4*)&dst[i0];
        atomicAdd(&deg[d.x], 1);
        atomicAdd(&deg[d.y], 1);
        atomicAdd(&deg[d.z], 1);
        atomicAdd(&deg[d.w], 1);
    } else {
        for (int e = i0; e < E; ++e) atomicAdd(&deg[dst[e]], 1);
    }
}
__global__ __launch_bounds__(1024) void k_scanA(const int* __restrict__ deg, int n,
                                                int* __restrict__ out, int* __restrict__ bsum) {
    __shared__ int wsum[16];
    int t = threadIdx.x, w = t >> 6, lane = t & 63;
    int i0 = blockIdx.x * 4096 + t * 4;
    int4 v = make_int4(0, 0, 0, 0);
    if (i0 + 3 < n) v = *(const int4*)&deg[i0];
    else {
        if (i0 < n)     v.x = deg[i0];
        if (i0 + 1 < n) v.y = deg[i0 + 1];
        if (i0 + 2 < n) v.z = deg[i0 + 2];
    }
    int tsum = v.x + v.y + v.z + v.w;
    int s = tsum;
#pragma unroll
    for (int o = 1; o < 64; o <<= 1) { int u = __shfl_up(s, o, 64); if (lane >= o) s += u; }
    if (lane == 63) wsum[w] = s;
    __syncthreads();
    if (w == 0 && lane < 16) {
        int ws = wsum[lane];
#pragma unroll
        for (int o = 1; o < 16; o <<= 1) { int u = __shfl_up(ws, o, 64); if (lane >= o) ws += u; }
        wsum[lane] = ws;
    }
    __syncthreads();
    int woff = (w == 0) ? 0 : wsum[w - 1];
    int p = woff + s - tsum;
    if (i0 + 3 < n) {
        int4 o4; o4.x = p; o4.y = p + v.x; o4.z = p + v.x + v.y; o4.w = p + v.x + v.y + v.z;
        *(int4*)&out[i0] = o4;
    } else {
        int pp = p;
        if (i0 < n)     { out[i0] = pp;     pp += v.x; }
        if (i0 + 1 < n) { out[i0 + 1] = pp; pp += v.y; }
        if (i0 + 2 < n) { out[i0 + 2] = pp; }
    }
    if (t == 0) bsum[blockIdx.x] = wsum[15];
}
__global__ void k_scanB(int* __restrict__ bsum, int nb, int* __restrict__ total) {
    int lane = threadIdx.x;
    int v = (lane < nb) ? bsum[lane] : 0;
    int s = v;
#pragma unroll
    for (int o = 1; o < 64; o <<= 1) { int u = __shfl_up(s, o, 64); if (lane >= o) s += u; }
    if (lane < nb) bsum[lane] = s - v;
    if (lane == 63) total[0] = s;
}
__global__ void k_scanC(int* __restrict__ rowptr, int* __restrict__ cursor,
                        const int* __restrict__ boff, int n) {
    int i = blockIdx.x * 256 + threadIdx.x;
    if (i < n) {
        int r = rowptr[i] + boff[i >> 12];
        rowptr[i] = r; cursor[i] = r;
    }
}
// 4 edges/thread, vectorized reads
__global__ void k_scatter(const int* __restrict__ srcp, const int* __restrict__ dstp, int E,
                          int* __restrict__ cursor, int* __restrict__ col) {
    int i0 = (blockIdx.x * 256 + threadIdx.x) * 4;
    if (i0 + 3 < E) {
        int4 s = *(const int4*)&srcp[i0];
        int4 d = *(const int4*)&dstp[i0];
        col[atomicAdd(&cursor[d.x], 1)] = s.x;
        col[atomicAdd(&cursor[d.y], 1)] = s.y;
        col[atomicAdd(&cursor[d.z], 1)] = s.z;
        col[atomicAdd(&cursor[d.w], 1)] = s.w;
    } else {
        for (int e = i0; e < E; ++e)
            col[atomicAdd(&cursor[dstp[e]], 1)] = srcp[e];
    }
}

// ---------- fused: input proj + prelu0 + conv1 lin + att scalars (R10 verbatim) ----------
__global__ __launch_bounds__(256) void k_fused1(
    const float* __restrict__ x, const float* __restrict__ numx, const float* __restrict__ numm,
    const float* __restrict__ txt, const float* __restrict__ txtm,
    const float* __restrict__ numw, const float* __restrict__ numb,
    const float* __restrict__ txtw, const float* __restrict__ txtb,
    const float* __restrict__ nodew, const float* __restrict__ nodeb,
    const float* __restrict__ pa,
    const float* __restrict__ W1, const float* __restrict__ atts, const float* __restrict__ attd,
    u16* __restrict__ xh, float* __restrict__ asrc, float* __restrict__ adst) {
    __shared__ u16 sw[128 * 136];
    __shared__ u16 sh[4][16 * 136];
    int tid = threadIdx.x, w = tid >> 6, lane = tid & 63, quad = lane >> 4, l16 = lane & 15;
    int nb = blockIdx.x * 64 + w * 16;
    f32x4 acc[8];
#pragma unroll
    for (int ct = 0; ct < 8; ++ct) { f32x4 z = {0.f, 0.f, 0.f, 0.f}; acc[ct] = z; }

    for (int chunk = 0; chunk < 3; ++chunk) {
        __syncthreads();
        stage256_f32(txtw, 384, chunk * 128, sw, tid);
        __syncthreads();
#pragma unroll
        for (int ks = 0; ks < 4; ++ks) {
            bf16x8 a0 = ldA_f32(txt, (size_t)(nb + l16) * 384 + chunk * 128 + ks * 32 + quad * 8);
#pragma unroll
            for (int ct = 0; ct < 8; ++ct)
                acc[ct] = __builtin_amdgcn_mfma_f32_16x16x32_bf16(
                    a0, ldB(sw, ct, ks, l16, quad), acc[ct], 0, 0, 0);
        }
    }
#pragma unroll
    for (int r = 0; r < 4; ++r) {
        float tm = txtm[nb + quad * 4 + r];
#pragma unroll
        for (int ct = 0; ct < 8; ++ct) acc[ct][r] *= tm;
    }
    __syncthreads();
    stage256_f32(nodew, 128, 0, sw, tid);
    __syncthreads();
#pragma unroll
    for (int ks = 0; ks < 4; ++ks) {
        bf16x8 a0 = ldA_f32(x, (size_t)(nb + l16) * 128 + ks * 32 + quad * 8);
#pragma unroll
        for (int ct = 0; ct < 8; ++ct)
            acc[ct] = __builtin_amdgcn_mfma_f32_16x16x32_bf16(
                a0, ldB(sw, ct, ks, l16, quad), acc[ct], 0, 0, 0);
    }
    float nm[4];
#pragma unroll
    for (int r = 0; r < 4; ++r) {
        int n = nb + quad * 4 + r;
        nm[r] = numx[n] * numm[n];
    }
#pragma unroll
    for (int ct = 0; ct < 8; ++ct) {
        int c = ct * 16 + l16;
        float cw = numw[c];
        float cb = numb[c] + txtb[c] + nodeb[c];
        float pav = pa[c];
#pragma unroll
        for (int r = 0; r < 4; ++r) {
            float v = acc[ct][r] + nm[r] * cw + cb;
            v = v >= 0.f ? v : pav * v;
            sh[w][(quad * 4 + r) * 136 + c] = f2bf(v);
        }
    }
    __syncthreads();
    stage256_f32(W1, 128, 0, sw, tid);
    __syncthreads();
    f32x4 a2[8];
#pragma unroll
    for (int ct = 0; ct < 8; ++ct) { f32x4 z = {0.f, 0.f, 0.f, 0.f}; a2[ct] = z; }
#pragma unroll
    for (int ks = 0; ks < 4; ++ks) {
        bf16x8 a0 = ld16B(sh[w], l16 * 136 + ks * 32 + quad * 8);
#pragma unroll
        for (int ct = 0; ct < 8; ++ct)
            a2[ct] = __builtin_amdgcn_mfma_f32_16x16x32_bf16(
                a0, ldB(sw, ct, ks, l16, quad), a2[ct], 0, 0, 0);
    }
#pragma unroll
    for (int ct = 0; ct < 8; ++ct) {
        int c = ct * 16 + l16;
#pragma unroll
        for (int r = 0; r < 4; ++r)
            xh[(size_t)(nb + quad * 4 + r) * 128 + c] = f2bf(a2[ct][r]);
    }
    float as_[8], ad_[8];
#pragma unroll
    for (int ct = 0; ct < 8; ++ct) {
        int c = ct * 16 + l16;
        as_[ct] = atts[c];
        ad_[ct] = attd[c];
    }
#pragma unroll
    for (int hh = 0; hh < 4; ++hh) {
        float vs[4], vd[4];
#pragma unroll
        for (int r = 0; r < 4; ++r) {
            vs[r] = a2[2 * hh][r] * as_[2 * hh] + a2[2 * hh + 1][r] * as_[2 * hh + 1];
            vd[r] = a2[2 * hh][r] * ad_[2 * hh] + a2[2 * hh + 1][r] * ad_[2 * hh + 1];
        }
#pragma unroll
        for (int o = 1; o <= 8; o <<= 1) {
#pragma unroll
            for (int r = 0; r < 4; ++r) {
                vs[r] += __shfl_xor(vs[r], o, 64);
                vd[r] += __shfl_xor(vd[r], o, 64);
            }
        }
        if ((l16 >> 2) == hh) {
            int r = l16 & 3;
            float ss = (r == 0) ? vs[0] : (r == 1) ? vs[1] : (r == 2) ? vs[2] : vs[3];
            float dd = (r == 0) ? vd[0] : (r == 1) ? vd[1] : (r == 2) ? vd[2] : vd[3];
            int n = nb + quad * 4 + r;
            asrc[n * 4 + hh] = ss;
            adst[n * 4 + hh] = dd;
        }
    }
}

// ---------- xh = h @ W^T (MFMA) + attention scalars (R10 verbatim) ----------
__global__ __launch_bounds__(256) void k_xh(
    const u16* __restrict__ h, const float* __restrict__ W,
    const float* __restrict__ att_s, const float* __restrict__ att_d,
    u16* __restrict__ xh, float* __restrict__ asrc, float* __restrict__ adst) {
    __shared__ u16 sw[128 * 136];
    int tid = threadIdx.x;
    int w = tid >> 6, lane = tid & 63, quad = lane >> 4, l16 = lane & 15;
    int nb = blockIdx.x * 64 + w * 16;
    f32x4 acc[8];
#pragma unroll
    for (int ct = 0; ct < 8; ++ct) { f32x4 z = {0.f, 0.f, 0.f, 0.f}; acc[ct] = z; }

    stage256_f32(W, 128, 0, sw, tid);
    __syncthreads();
#pragma unroll
    for (int ks = 0; ks < 4; ++ks) {
        bf16x8 a0 = ld16B(h, (size_t)(nb + l16) * 128 + ks * 32 + quad * 8);
#pragma unroll
        for (int ct = 0; ct < 8; ++ct)
            acc[ct] = __builtin_amdgcn_mfma_f32_16x16x32_bf16(
                a0, ldB(sw, ct, ks, l16, quad), acc[ct], 0, 0, 0);
    }
#pragma unroll
    for (int ct = 0; ct < 8; ++ct) {
        int c = ct * 16 + l16;
#pragma unroll
        for (int r = 0; r < 4; ++r) {
            int n = nb + quad * 4 + r;
            xh[(size_t)n * 128 + c] = f2bf(acc[ct][r]);
        }
    }
    float as_[8], ad_[8];
#pragma unroll
    for (int ct = 0; ct < 8; ++ct) {
        int c = ct * 16 + l16;
        as_[ct] = att_s[c];
        ad_[ct] = att_d[c];
    }
#pragma unroll
    for (int hh = 0; hh < 4; ++hh) {
        float vs[4], vd[4];
#pragma unroll
        for (int r = 0; r < 4; ++r) {
            vs[r] = acc[2 * hh][r] * as_[2 * hh] + acc[2 * hh + 1][r] * as_[2 * hh + 1];
            vd[r] = acc[2 * hh][r] * ad_[2 * hh] + acc[2 * hh + 1][r] * ad_[2 * hh + 1];
        }
#pragma unroll
        for (int o = 1; o <= 8; o <<= 1) {
#pragma unroll
            for (int r = 0; r < 4; ++r) {
                vs[r] += __shfl_xor(vs[r], o, 64);
                vd[r] += __shfl_xor(vd[r], o, 64);
            }
        }
        if ((l16 >> 2) == hh) {
            int r = l16 & 3;
            float ss = (r == 0) ? vs[0] : (r == 1) ? vs[1] : (r == 2) ? vs[2] : vs[3];
            float dd = (r == 0) ? vd[0] : (r == 1) ? vd[1] : (r == 2) ? vd[2] : vd[3];
            int n = nb + quad * 4 + r;
            asrc[n * 4 + hh] = ss;
            adst[n * 4 + hh] = dd;
        }
    }
}

// ---------- per-dst softmax + aggregation + bias + LN + prelu (+ head) ----------
// 4 nodes/block = 4 waves; per-wave private LDS slices, NO block barriers (all LDS
// sharing is intra-wave = lockstep-safe). 8-deep unrolled gather (8 loads in flight).
__global__ __launch_bounds__(256) void k_agg(
    const u16* __restrict__ xh, const float* __restrict__ asrc, const float* __restrict__ adst,
    const int* __restrict__ rowptr, const int* __restrict__ col,
    const float* __restrict__ bias, const float* __restrict__ g, const float* __restrict__ b,
    const float* __restrict__ pa, u16* __restrict__ hnext,
    const float* __restrict__ outw, const float* __restrict__ outb, float* __restrict__ outy,
    int is_final, int N) {
    __shared__ int   scol[4][64];
    __shared__ float scoef[4][64][4];
    int tid = threadIdx.x, w = tid >> 6, lane = tid & 63;
    int n = blockIdx.x * 4 + w;
    if (n >= N) return;                      // wave-uniform exit, no barriers used
    int beg = rowptr[n], end = rowptr[n + 1];
    const float4* asrc4 = (const float4*)asrc;

    float4 adv = ((const float4*)adst)[n];
    float ad[4] = { adv.x, adv.y, adv.z, adv.w };
    float4 asv = asrc4[n];
    float els[4];
#pragma unroll
    for (int h = 0; h < 4; h++) {
        float a = ((const float*)&asv)[h] + ad[h];
        a = a >= 0.f ? a : 0.2f * a;
        els[h] = __expf(a);
    }
    int hh = lane >> 4;
    u32 vself = ((const u32*)(xh + (size_t)n * 128))[lane];
    float acc0 = els[hh] * bf2f(vself & 0xffffu);
    float acc1 = els[hh] * bf2f(vself >> 16);
    float a0b = 0.f, a1b = 0.f, a0c = 0.f, a1c = 0.f, a0d = 0.f, a1d = 0.f;
    float l[4] = { 0.f, 0.f, 0.f, 0.f };

    for (int base = beg; base < end; base += 64) {
        int e = base + lane;
        int cnt = min(64, end - base);
        if (e < end) {
            int s = col[e];
            float4 av = asrc4[s];
            scol[w][lane] = s;
            float cf[4];
#pragma unroll
            for (int h = 0; h < 4; h++) {
                float a = ((const float*)&av)[h] + ad[h];
                a = a >= 0.f ? a : 0.2f * a;
                cf[h] = __expf(a);
                l[h] += cf[h];
            }
            *(float4*)scoef[w][lane] = make_float4(cf[0], cf[1], cf[2], cf[3]);
        }
        // intra-wave LDS handoff: lockstep wave, compiler inserts lgkmcnt waits
        int j = 0;
        for (; j + 7 < cnt; j += 8) {
            int s0 = scol[w][j],     s1 = scol[w][j + 1];
            int s2 = scol[w][j + 2], s3 = scol[w][j + 3];
            int s4 = scol[w][j + 4], s5 = scol[w][j + 5];
            int s6 = scol[w][j + 6], s7 = scol[w][j + 7];
            u32 v0 = ((const u32*)(xh + (size_t)s0 * 128))[lane];
            u32 v1 = ((const u32*)(xh + (size_t)s1 * 128))[lane];
            u32 v2 = ((const u32*)(xh + (size_t)s2 * 128))[lane];
            u32 v3 = ((const u32*)(xh + (size_t)s3 * 128))[lane];
            u32 v4 = ((const u32*)(xh + (size_t)s4 * 128))[lane];
            u32 v5 = ((const u32*)(xh + (size_t)s5 * 128))[lane];
            u32 v6 = ((const u32*)(xh + (size_t)s6 * 128))[lane];
            u32 v7 = ((const u32*)(xh + (size_t)s7 * 128))[lane];
            float c0 = scoef[w][j][hh],     c1 = scoef[w][j + 1][hh];
            float c2 = scoef[w][j + 2][hh], c3 = scoef[w][j + 3][hh];
            float c4 = scoef[w][j + 4][hh], c5 = scoef[w][j + 5][hh];
            float c6 = scoef[w][j + 6][hh], c7 = scoef[w][j + 7][hh];
            acc0 += c0 * bf2f(v0 & 0xffffu);  acc1 += c0 * bf2f(v0 >> 16);
            a0b  += c1 * bf2f(v1 & 0xffffu);  a1b  += c1 * bf2f(v1 >> 16);
            a0c  += c2 * bf2f(v2 & 0xffffu);  a1c  += c2 * bf2f(v2 >> 16);
            a0d  += c3 * bf2f(v3 & 0xffffu);  a1d  += c3 * bf2f(v3 >> 16);
            acc0 += c4 * bf2f(v4 & 0xffffu);  acc1 += c4 * bf2f(v4 >> 16);
            a0b  += c5 * bf2f(v5 & 0xffffu);  a1b  += c5 * bf2f(v5 >> 16);
            a0c  += c6 * bf2f(v6 & 0xffffu);  a1c  += c6 * bf2f(v6 >> 16);
            a0d  += c7 * bf2f(v7 & 0xffffu);  a1d  += c7 * bf2f(v7 >> 16);
        }
        for (; j + 1 < cnt; j += 2) {
            int s0 = scol[w][j], s1 = scol[w][j + 1];
            u32 v0 = ((const u32*)(xh + (size_t)s0 * 128))[lane];
            u32 v1 = ((const u32*)(xh + (size_t)s1 * 128))[lane];
            float c0 = scoef[w][j][hh], c1 = scoef[w][j + 1][hh];
            acc0 += c0 * bf2f(v0 & 0xffffu);  acc1 += c0 * bf2f(v0 >> 16);
            a0b  += c1 * bf2f(v1 & 0xffffu);  a1b  += c1 * bf2f(v1 >> 16);
        }
        if (j < cnt) {
            int s0 = scol[w][j];
            float c0 = scoef[w][j][hh];
            u32 v0 = ((const u32*)(xh + (size_t)s0 * 128))[lane];
            acc0 += c0 * bf2f(v0 & 0xffffu);
            acc1 += c0 * bf2f(v0 >> 16);
        }
    }
    acc0 += a0b + a0c + a0d;
    acc1 += a1b + a1c + a1d;

    float L[4];
#pragma unroll
    for (int h = 0; h < 4; h++) L[h] = wred_sum(l[h]) + els[h];
    float inv = 1.f / L[hh];
    acc0 *= inv;
    acc1 *= inv;

    int c0i = 2 * lane;
    float2 bi = *(const float2*)(bias + c0i);
    acc0 += bi.x; acc1 += bi.y;

    float mean = wred_sum(acc0 + acc1) * (1.f / 128.f);
    float d0 = acc0 - mean, d1 = acc1 - mean;
    float var = wred_sum(d0 * d0 + d1 * d1) * (1.f / 128.f);
    float rstd = rsqrtf(var + 1e-5f);
    float2 gg = *(const float2*)(g + c0i);
    float2 bb = *(const float2*)(b + c0i);
    float2 pp = *(const float2*)(pa + c0i);
    float y0 = d0 * rstd * gg.x + bb.x;
    float y1 = d1 * rstd * gg.y + bb.y;
    y0 = y0 >= 0.f ? y0 : pp.x * y0;
    y1 = y1 >= 0.f ? y1 : pp.y * y1;

    if (is_final) {
        float2 ow = *(const float2*)(outw + c0i);
        float dot = wred_sum(y0 * ow.x + y1 * ow.y);
        if (lane == 0) outy[n] = dot + outb[0];
    } else {
        ((u32*)(hnext + (size_t)n * 128))[lane] = (u32)f2bf(y0) | ((u32)f2bf(y1) << 16);
    }
}

// ---------- launch ----------
extern "C" void kernel_launch(void* const* d_in, const int* in_sizes, int n_in,
                              void* d_out, int out_size, void* d_ws, size_t ws_size,
                              hipStream_t stream) {
    const int N = in_sizes[2];          // num_mask has N elements
    const int E = in_sizes[5] / 2;      // edge_index is [2,E]

    const float* x      = (const float*)d_in[0];
    const float* numx   = (const float*)d_in[1];
    const float* numm   = (const float*)d_in[2];
    const float* txt    = (const float*)d_in[3];
    const float* txtm   = (const float*)d_in[4];
    const int*   ei     = (const int*)d_in[5];
    const float* numw   = (const float*)d_in[6];
    const float* numb   = (const float*)d_in[7];
    const float* txtw   = (const float*)d_in[8];
    const float* txtb   = (const float*)d_in[9];
    const float* nodew  = (const float*)d_in[10];
    const float* nodeb  = (const float*)d_in[11];
    const float* pa0    = (const float*)d_in[12];
    const float* conv1w = (const float*)d_in[13];
    const float* atts1  = (const float*)d_in[14];
    const float* attd1  = (const float*)d_in[15];
    const float* bias1  = (const float*)d_in[16];
    const float* g1     = (const float*)d_in[17];
    const float* b1     = (const float*)d_in[18];
    const float* pa1    = (const float*)d_in[19];
    const float* conv2w = (const float*)d_in[20];
    const float* atts2  = (const float*)d_in[21];
    const float* attd2  = (const float*)d_in[22];
    const float* bias2  = (const float*)d_in[23];
    const float* g2     = (const float*)d_in[24];
    const float* b2     = (const float*)d_in[25];
    const float* pa2    = (const float*)d_in[26];
    const float* outw   = (const float*)d_in[27];
    const float* outb   = (const float*)d_in[28];

    const int* srcp = ei;
    const int* dstp = ei + E;

    char* p = (char*)d_ws;
    auto alloc = [&](size_t bytes) -> void* {
        void* q = (void*)p;
        p += (bytes + 255) & ~(size_t)255;
        return q;
    };
    u16*   hA     = (u16*)alloc((size_t)N * 128 * 2);   // h1 (bf16)
    u16*   hB     = (u16*)alloc((size_t)N * 128 * 2);   // xh1 / xh2 (bf16)
    float* asrc   = (float*)alloc((size_t)N * 4 * 4);
    float* adst   = (float*)alloc((size_t)N * 4 * 4);
    int*   deg    = (int*)alloc((size_t)N * 4);
    int*   rowptr = (int*)alloc((size_t)(N + 1) * 4);
    int*   cursor = (int*)alloc((size_t)N * 4);
    int*   col    = (int*)alloc((size_t)E * 4);
    int*   bsum   = (int*)alloc(64 * 4);

    // CSR by dst (self-loops handled analytically in k_agg)
    const int nbScan = (N + 4095) / 4096;
    k_zero<<<(N + 255) / 256, 256, 0, stream>>>(deg, N);
    k_hist<<<(E / 4 + 255) / 256, 256, 0, stream>>>(dstp, E, deg);
    k_scanA<<<nbScan, 1024, 0, stream>>>(deg, N, rowptr, bsum);
    k_scanB<<<1, 64, 0, stream>>>(bsum, nbScan, rowptr + N);
    k_scanC<<<(N + 255) / 256, 256, 0, stream>>>(rowptr, cursor, bsum, N);
    k_scatter<<<(E / 4 + 255) / 256, 256, 0, stream>>>(srcp, dstp, E, cursor, col);

    const int gProj = N / 64;   // 625 for N=40000
    const int gAgg  = (N + 3) / 4;

    // layer 1: fused input proj + prelu0 + conv1 lin (h0 never touches HBM)
    k_fused1<<<gProj, 256, 0, stream>>>(x, numx, numm, txt, txtm, numw, numb,
                                        txtw, txtb, nodew, nodeb, pa0,
                                        conv1w, atts1, attd1, hB, asrc, adst);
    k_agg<<<gAgg, 256, 0, stream>>>(hB, asrc, adst, rowptr, col, bias1, g1, b1, pa1,
                                    hA, nullptr, nullptr, nullptr, 0, N);

    // layer 2
    k_xh<<<gProj, 256, 0, stream>>>(hA, conv2w, atts2, attd2, hB, asrc, adst);
    k_agg<<<gAgg, 256, 0, stream>>>(hB, asrc, adst, rowptr, col, bias2, g2, b2, pa2,
                                    nullptr, outw, outb, (float*)d_out, 1, N);
}